// Round 13
// baseline (1981.177 us; speedup 1.0000x reference)
//
#include <hip/hip_runtime.h>

#ifndef M_PI
#define M_PI 3.14159265358979323846
#endif

#define T_DATA 20000
#define E_NO_C 2000
#define I_NO_C 500
#define SUB 16
#define TNO 200
#define NGRP 5000   // 4-step groups
#define NSUP 2500   // 8-step super-groups

typedef float v2f __attribute__((ext_vector_type(2)));

template <bool B> struct BC { static constexpr bool v = B; };

// quad butterfly reduction on the VALU pipe (DPP quad_perm), no LDS traffic.
__device__ __forceinline__ float quad_sum(float v) {
  int a = __builtin_amdgcn_mov_dpp(__float_as_int(v), 177, 0xf, 0xf, true);
  v += __int_as_float(a);
  int b = __builtin_amdgcn_mov_dpp(__float_as_int(v), 78, 0xf, 0xf, true);
  v += __int_as_float(b);
  return v;
}

// Drain barrier: LDS writes visible after this (lgkmcnt(0) + s_barrier).
__device__ __forceinline__ void bar_drain() {
  asm volatile("s_waitcnt lgkmcnt(0)" ::: "memory");
  __builtin_amdgcn_s_barrier();
  asm volatile("" ::: "memory");
}
// Raw barrier: rendezvous only. Use when this wave's pending LDS ops are not
// consumed by anyone until a LATER drain barrier.
__device__ __forceinline__ void bar_raw() {
  asm volatile("" ::: "memory");
  __builtin_amdgcn_s_barrier();
  asm volatile("" ::: "memory");
}

// ---------------- Kernel A: filter kernels (e, i, spk, hist) -> d_out[320000..] ----------------
__global__ void filters_k(const float* __restrict__ Tau_e, const float* __restrict__ Tau_i,
                          const float* __restrict__ W_e,  const float* __restrict__ W_i,
                          const float* __restrict__ D_e,  const float* __restrict__ D_i,
                          const float* __restrict__ Tau_spk, const float* __restrict__ W_spk,
                          const float* __restrict__ W_hist,
                          float* __restrict__ filt_out) {
  int id = blockIdx.x * blockDim.x + threadIdx.x;
  if (id >= 64 * TNO) return;
  int r = id / TNO, x = id % TNO;
  int s = r & 15, kind = r >> 4;
  double xd = (double)x;
  double val;
  if (kind == 0) {
    double te = xd - exp((double)D_e[s]); te = te > 0.0 ? te : 0.0;
    double tt = te / exp((double)Tau_e[s]);
    val = tt * exp(-tt) * exp((double)W_e[s]);
  } else if (kind == 1) {
    double ti = xd - exp((double)D_i[s]); ti = ti > 0.0 ? ti : 0.0;
    double tt = ti / exp((double)Tau_i[s]);
    val = -tt * exp(-tt) * exp((double)W_i[s]);
  } else if (kind == 2) {
    double tt = xd / exp((double)Tau_spk[s]);
    val = tt * exp(-tt) * exp((double)W_spk[s]);
  } else {
    double raw = 4.0 * log(xd + 1.0);
    double acc = 0.0;
    for (int i = 0; i < 16; ++i) {
      double phi = (M_PI / 2.0) * (double)i;
      double b = (raw < phi - M_PI || raw > phi + M_PI) ? 0.0
                                                        : (0.5 * cos(raw - phi) + 0.5);
      acc += (double)W_hist[s * 16 + i] * b;
    }
    val = acc;
  }
  filt_out[id] = (float)val;
}

// ---------------- Kernel B: syn = S @ C^T, C staged in LDS tiles ----------------
#define ETILE 500
__global__ __launch_bounds__(256) void synmm_k(const float* __restrict__ S,
                                               const float* __restrict__ C,
                                               float* __restrict__ out, int E) {
  __shared__ __align__(16) float Cs[16][ETILE];
  int tid = threadIdx.x;
  int s = tid & 15, tt = tid >> 4;
  long t = (long)blockIdx.x * 16 + tt;
  const float* Srow = S + t * E;
  float acc = 0.f;
  for (int tb = 0; tb < E; tb += ETILE) {
    __syncthreads();
    for (int i = tid; i < 16 * ETILE; i += 256) {
      int s2 = i / ETILE, k2 = i - s2 * ETILE;
      Cs[s2][k2] = C[(long)s2 * E + tb + k2];
    }
    __syncthreads();
    const float* Crow = &Cs[s][0];
    const float* Sp = Srow + tb;
#pragma unroll 2
    for (int e = 0; e < ETILE; e += 4) {
      float4 a = *(const float4*)(Sp + e);
      float4 c = *(const float4*)(Crow + e);
      acc = fmaf(a.x, c.x, acc); acc = fmaf(a.y, c.y, acc);
      acc = fmaf(a.z, c.z, acc); acc = fmaf(a.w, c.w, acc);
    }
  }
  out[t * 16 + s] = acc;
}

// ---------------- Kernel C: causal depthwise conv + Theta, [t][s] layout ----------------
__global__ void conv_k(const float* __restrict__ syn_e, const float* __restrict__ syn_i,
                       const float* __restrict__ filt, const float* __restrict__ Theta,
                       float* __restrict__ synTh) {
  __shared__ float ek[16][201];
  __shared__ float ik[16][201];
  int tid = threadIdx.x;
  for (int idx = tid; idx < 16 * TNO; idx += 256) {
    ek[idx / TNO][idx % TNO] = filt[idx];
    ik[idx / TNO][idx % TNO] = filt[16 * TNO + idx];
  }
  __syncthreads();
  int s = tid & 15, tt = tid >> 4;
  int t = blockIdx.x * 16 + tt;
  float acc = Theta[s];
  if (t >= TNO) {
#pragma unroll 4
    for (int j = 0; j < TNO; ++j) {
      int u = t - 1 - j;
      acc += ek[s][j] * syn_e[u * 16 + s] + ik[s][j] * syn_i[u * 16 + s];
    }
  } else {
    for (int j = 0; j < t; ++j) {
      int u = t - 1 - j;
      acc += ek[s][j] * syn_e[u * 16 + s] + ik[s][j] * syn_i[u * 16 + s];
    }
  }
  synTh[t * 16 + s] = acc;
}

// ---------------- Kernel D: 8-wave, 2-barrier interval (R22 = R21 + raw-carry) ----------------
// R21 verbatim with ONE edit, scan wave only: phase 2 no longer assembles
// ocA1-3/uB. The raw ds_read components (fsA.y-w, fsB, synA.y-w, synB) are
// carried across END in persistent registers; the assembly (12+4 adds, exact
// same trees) happens at the TOP of next phase 1 as stall filler (ocA1 not
// consumed until STEP 2, ~110cyc in). Phase 2 = 4 ds_reads + ocA0 assembly
// (needed at STEP 1) + S-rotation. Every held variable is consumed before
// its overwrite (verified ordering) -> no extra movs. Zero math changes.
__global__ __launch_bounds__(512, 1) void scan22_k(const float* __restrict__ synTh,
                                                   const float* __restrict__ filt,
                                                   const float* __restrict__ C_den,
                                                   const float* __restrict__ Tau_spk,
                                                   const float* __restrict__ W_spk,
                                                   float* __restrict__ spk_out) {
  __shared__ __align__(16) float ring[16][452];        // [s][pos], mirror pos+256 for pos<192
  __shared__ __align__(16) float oPartF[2][5][64][2];  // [slot][farwave][4s+K][parity]
  __shared__ __align__(16) float farsumF[2][2][64];    // [buf][parity][4s+K]
  __shared__ __align__(16) float synStage[2][4][16][20]; // [buf][g&3][s][K(+pad)]
  const int tid = threadIdx.x;
  const int widx = tid >> 6;
  const int l = tid & 63;
  const int s = l & 15, q = l >> 4;

  for (int i = tid; i < 16 * 452; i += 512) (&ring[0][0])[i] = 0.f;
  for (int i = tid; i < 2 * 5 * 64 * 2; i += 512) (&oPartF[0][0][0][0])[i] = 0.f;
  for (int i = tid; i < 2 * 2 * 64; i += 512) (&farsumF[0][0][0])[i] = 0.f;
  __syncthreads();
  if (widx == 7) {  // merged: preload synTh old-groups 0..3 (256 floats)
    int e0 = 4 * l;
    float4 v = *(const float4*)&synTh[e0];
    int t0 = e0 >> 4, s0 = e0 & 15;
    int g = t0 >> 2, K = t0 & 3;
    synStage[0][g & 3][s0 + 0][K] = v.x;
    synStage[0][g & 3][s0 + 1][K] = v.y;
    synStage[0][g & 3][s0 + 2][K] = v.z;
    synStage[0][g & 3][s0 + 3][K] = v.w;
  }
  __syncthreads();

  if (widx == 0) {
    // ================= scan wave (SIMD0, alone) =================
    const float* hrow = filt + (48 + s) * TNO;
    float hk[15];
#pragma unroll
    for (int i = 0; i < 15; ++i) hk[i] = hrow[i];

    float t0v = Tau_spk[0], w0v = W_spk[0];
    bool okrow = (Tau_spk[s] == t0v) && (W_spk[s] == w0v);
    unsigned cd = 0u;
#pragma unroll
    for (int j = 0; j < 16; ++j) {
      float cv = C_den[s * 16 + j];
      okrow = okrow && (cv == 0.f || cv == 1.f);
      cd |= (cv != 0.f) ? (1u << j) : 0u;
    }
    const bool uni = (bool)__all((int)okrow);

    const double tau  = exp((double)Tau_spk[s]);
    const double aa   = exp(-1.0 / tau);
    const double c2a  = exp((double)W_spk[s]) * aa / tau;  // K[d]=C(d-1)a^(d-1), C=w/tau
    const double twoa = 2.0 * aa;
    const double na2  = -aa * aa;

    double twoa4[4], na24[4], c2a4[4], yd0a[4], yd1a[4];
    float cden4[4];
#pragma unroll
    for (int r = 0; r < 4; ++r) {
      int j = 4 * q + r;
      double tj = exp((double)Tau_spk[j]);
      double aj = exp(-1.0 / tj);
      twoa4[r] = 2.0 * aj; na24[r] = -aj * aj;
      c2a4[r]  = exp((double)W_spk[j]) * aj / tj;
      yd0a[r] = 0.0; yd1a[r] = 0.0;
      cden4[r] = C_den[s * 16 + j];
    }

    double zA = 0.0, zB = 0.0, zP = 0.0;   // zP = fma(twoa,zB,na2*zA), off-chain
    float mixu = 0.f, mix1 = 0.f;
    float sgPrev = 0.f;
    float S0 = 0.f, S1 = 0.f, S2 = 0.f, S3 = 0.f;  // group 2M-1 spikes

    // ---- persistent cross-interval carries (consumed before overwrite) ----
    float ocA0h;                                    // assembled in phase 2
    float fsA1h, fsA2h, fsA3h;                      // raw farsum A components
    float fsB0h, fsB1h, fsB2h, fsB3h;               // raw farsum B
    float synA1h, synA2h, synA3h;                   // raw syn A components
    float synB0h, synB1h, synB2h, synB3h;           // raw syn B
    float nrA0h = 0.f, nrA1h = 0.f, nrA2h = 0.f, nrA3h = 0.f;
    float cA0h = 0.f, cA1h = 0.f, cA2h = 0.f, cA3h = 0.f;
    float ccA0h = 0.f, ccA1h = 0.f, ccA2h = 0.f, ccA3h = 0.f;
    float nrB0h = 0.f, nrB1h = 0.f, nrB2h = 0.f, nrB3h = 0.f;
    float ccB0h = 0.f, ccB1h = 0.f, ccB2h = 0.f, ccB3h = 0.f;
    {   // priming (M=0): trees are zero; raw reads from zeroed/preloaded LDS
      float4 fsA_r = *(const float4*)&farsumF[0][0][4 * s];
      float4 fsB_r = *(const float4*)&farsumF[0][1][4 * s];
      float4 synA_r = *(const float4*)&synStage[0][0][s][0];
      float4 synB_r = *(const float4*)&synStage[0][1][s][0];
      float z0 = 0.f;
      ocA0h = ((z0 + fsA_r.x) + (synA_r.x + z0)) + z0;
      fsA1h = fsA_r.y; fsA2h = fsA_r.z; fsA3h = fsA_r.w;
      fsB0h = fsB_r.x; fsB1h = fsB_r.y; fsB2h = fsB_r.z; fsB3h = fsB_r.w;
      synA1h = synA_r.y; synA2h = synA_r.z; synA3h = synA_r.w;
      synB0h = synB_r.x; synB1h = synB_r.y; synB2h = synB_r.z; synB3h = synB_r.w;
    }

#define STEP(SGD, PRE, SGOUT)                                                 \
    {                                                                         \
      float sub = fmaf(hk[0], (SGD), (PRE));                                  \
      unsigned long long bal = __ballot(sub > 0.f);                           \
      float sg = sub > 0.f ? 1.f : 0.f;                                       \
      if constexpr (UNI) {                                                    \
        unsigned xm = (unsigned)bal & cd;  /* cd bits 0-15 only */            \
        double zc = fma(c2a, (double)__popc(xm), zP);                         \
        zA = zB; zB = zc;                                                     \
        zP = fma(twoa, zB, na2 * zA);                                         \
        mixu = (float)zA;                                                     \
      } else {                                                                \
        unsigned mk = (unsigned)bal & 0xFFFFu;                                \
        float p = 0.f;                                                        \
        _Pragma("unroll")                                                     \
        for (int r = 0; r < 4; ++r) {                                         \
          double xr = (double)((mk >> (4 * q + r)) & 1u);                     \
          double y2 = fma(twoa4[r], yd1a[r], fma(na24[r], yd0a[r], c2a4[r] * xr)); \
          yd0a[r] = yd1a[r]; yd1a[r] = y2;                                    \
          p = fmaf(cden4[r], (float)y2, p);                                   \
        }                                                                     \
        p += __shfl_xor(p, 16); p += __shfl_xor(p, 32);                       \
        float mixn = mix1; mix1 = p;                                          \
        mixu = mixn;                                                          \
      }                                                                       \
      (SGOUT) = sg;                                                           \
    }

    auto scan_loop = [&](auto uc) {
      constexpr bool UNI = decltype(uc)::v;
      for (int M = 0; M < NSUP; ++M) {
        // ---- phase-1 top filler: assemble ocA1-3 / uB from held raw values
        //      (exact R9 trees; ocA1 not consumed until STEP 2) ----
        float ocA1 = ((nrA1h + fsA1h) + (synA1h + cA1h)) + ccA1h;
        float ocA2 = ((nrA2h + fsA2h) + (synA2h + cA2h)) + ccA2h;
        float ocA3 = ((nrA3h + fsA3h) + (synA3h + cA3h)) + ccA3h;
        float uB0 = nrB0h + fsB0h;
        float uB1 = nrB1h + fsB1h;
        float uB2 = nrB2h + fsB2h;
        float uB3 = nrB3h + fsB3h;

        // ---------------- STEP chain A ----------------
        float SA0, SA1, SA2, SA3;
        STEP(sgPrev, ocA0h + mixu, SA0)
        float pend2 = hk[1] * SA0;
        float pend3 = hk[2] * SA0;
        STEP(SA0, ocA1 + mixu, SA1)
        pend3 = fmaf(hk[1], SA1, pend3);
        STEP(SA1, (ocA2 + mixu) + pend2, SA2)
        STEP(SA2, (ocA3 + mixu) + pend3, SA3)

        if (l < 16) {
          int u = (8 * M) & 255;
          float4 w0; w0.x = SA0; w0.y = SA1; w0.z = SA2; w0.w = SA3;
          *(float4*)&ring[s][u] = w0;
          if (u < 192) *(float4*)&ring[s][u + 256] = w0;
        }

        // B-group: only cB is fresh; rest held from last interval.
        float cB0 = fmaf(hk[1], SA2, fmaf(hk[2], SA1, hk[3] * SA0));
        float cB1 = fmaf(hk[1], SA3, fmaf(hk[2], SA2, fmaf(hk[3], SA1, hk[4] * SA0)));
        float cB2 = fmaf(hk[2], SA3, fmaf(hk[3], SA2, fmaf(hk[4], SA1, hk[5] * SA0)));
        float cB3 = fmaf(hk[3], SA3, fmaf(hk[4], SA2, fmaf(hk[5], SA1, hk[6] * SA0)));
        float ocB0 = (uB0 + (synB0h + cB0)) + ccB0h;
        float ocB1 = (uB1 + (synB1h + cB1)) + ccB1h;
        float ocB2 = (uB2 + (synB2h + cB2)) + ccB2h;
        float ocB3 = (uB3 + (synB3h + cB3)) + ccB3h;

        float SB0, SB1, SB2, SB3;
        STEP(SA3, ocB0 + mixu, SB0)
        float pend2b = hk[1] * SB0;
        float pend3b = hk[2] * SB0;
        STEP(SB0, ocB1 + mixu, SB1)
        pend3b = fmaf(hk[1], SB1, pend3b);
        STEP(SB1, (ocB2 + mixu) + pend2b, SB2)
        STEP(SB2, (ocB3 + mixu) + pend3b, SB3)

        if (l < 16) {
          int u = (8 * M + 4) & 255;
          float4 w0; w0.x = SB0; w0.y = SB1; w0.z = SB2; w0.w = SB3;
          *(float4*)&ring[s][u] = w0;
          if (u < 192) *(float4*)&ring[s][u + 256] = w0;
        }

        // stall-filler trees for M+1 (overwrite held vars — all already
        // consumed above this point). Exact R9 nests; S = group 2M-1.
        nrA0h = fmaf(hk[11], S0, fmaf(hk[10], S1, fmaf(hk[9], S2, hk[8] * S3)));
        nrA1h = fmaf(hk[12], S0, fmaf(hk[11], S1, fmaf(hk[10], S2, hk[9] * S3)));
        nrA2h = fmaf(hk[13], S0, fmaf(hk[12], S1, fmaf(hk[11], S2, hk[10] * S3)));
        nrA3h = fmaf(hk[14], S0, fmaf(hk[13], S1, fmaf(hk[12], S2, hk[11] * S3)));
        ccA0h = fmaf(hk[7], SA0, fmaf(hk[6], SA1, fmaf(hk[5], SA2, hk[4] * SA3)));
        ccA1h = fmaf(hk[8], SA0, fmaf(hk[7], SA1, fmaf(hk[6], SA2, hk[5] * SA3)));
        ccA2h = fmaf(hk[9], SA0, fmaf(hk[8], SA1, fmaf(hk[7], SA2, hk[6] * SA3)));
        ccA3h = fmaf(hk[10], SA0, fmaf(hk[9], SA1, fmaf(hk[8], SA2, hk[7] * SA3)));
        nrB0h = fmaf(hk[11], SA0, fmaf(hk[10], SA1, fmaf(hk[9], SA2, hk[8] * SA3)));
        nrB1h = fmaf(hk[12], SA0, fmaf(hk[11], SA1, fmaf(hk[10], SA2, hk[9] * SA3)));
        nrB2h = fmaf(hk[13], SA0, fmaf(hk[12], SA1, fmaf(hk[11], SA2, hk[10] * SA3)));
        nrB3h = fmaf(hk[14], SA0, fmaf(hk[13], SA1, fmaf(hk[12], SA2, hk[11] * SA3)));
        cA0h = fmaf(hk[1], SB2, fmaf(hk[2], SB1, hk[3] * SB0));
        cA1h = fmaf(hk[1], SB3, fmaf(hk[2], SB2, fmaf(hk[3], SB1, hk[4] * SB0)));
        cA2h = fmaf(hk[2], SB3, fmaf(hk[3], SB2, fmaf(hk[4], SB1, hk[5] * SB0)));
        cA3h = fmaf(hk[3], SB3, fmaf(hk[4], SB2, fmaf(hk[5], SB1, hk[6] * SB0)));
        ccB0h = fmaf(hk[7], SB0, fmaf(hk[6], SB1, fmaf(hk[5], SB2, hk[4] * SB3)));
        ccB1h = fmaf(hk[8], SB0, fmaf(hk[7], SB1, fmaf(hk[6], SB2, hk[5] * SB3)));
        ccB2h = fmaf(hk[9], SB0, fmaf(hk[8], SB1, fmaf(hk[7], SB2, hk[6] * SB3)));
        ccB3h = fmaf(hk[10], SB0, fmaf(hk[9], SB1, fmaf(hk[8], SB2, hk[7] * SB3)));

        bar_raw();   // ---- MID (ring writes drain at END)

        // ---------------- phase 2: reads + ocA0 assembly + rotation ----------------
        const int Mn = M + 1;
        const int gAn = 2 * Mn, gBn = 2 * Mn + 1;
        float4 fsA_r = *(const float4*)&farsumF[Mn & 1][0][4 * s];
        float4 fsB_r = *(const float4*)&farsumF[Mn & 1][1][4 * s];
        float4 synA_r = *(const float4*)&synStage[(gAn >> 2) & 1][gAn & 3][s][0];
        float4 synB_r = *(const float4*)&synStage[(gBn >> 2) & 1][gBn & 3][s][0];

        // ocA0 for M+1 (exact tree; needed at STEP 1 so assembled here)
        ocA0h = ((nrA0h + fsA_r.x) + (synA_r.x + cA0h)) + ccA0h;
        // raw carries (compiler coalesces — read regs become the held vars)
        fsA1h = fsA_r.y; fsA2h = fsA_r.z; fsA3h = fsA_r.w;
        fsB0h = fsB_r.x; fsB1h = fsB_r.y; fsB2h = fsB_r.z; fsB3h = fsB_r.w;
        synA1h = synA_r.y; synA2h = synA_r.z; synA3h = synA_r.w;
        synB0h = synB_r.x; synB1h = synB_r.y; synB2h = synB_r.z; synB3h = synB_r.w;

        S0 = SB0; S1 = SB1; S2 = SB2; S3 = SB3;
        sgPrev = SB3;
        bar_drain();   // ---- END (ring writes + phase2 reads drained)
      }
    };
    if (uni) scan_loop(BC<true>{});
    else     scan_loop(BC<false>{});
#undef STEP
  } else if (widx == 4) {
    // ================= dummy wave (SIMD0): barriers only =================
    for (int M = 0; M < NSUP; ++M) {
      bar_raw();
      bar_raw();
    }
  } else if (widx == 7) {
    // ======== merged wave (SIMD3): f5-inline + farsum + staging + writeback ========
    const int s2 = l >> 2, K = l & 3;
    const float* hrow = filt + (48 + s2) * TNO;
    float hc5[32];   // hc5[x] = hrow[12+K+x]
#pragma unroll
    for (int x = 0; x < 32; ++x) hc5[x] = hrow[12 + K + x];

    for (int M = 0; M < NSUP; ++M) {
      float4 vv;
      const bool doStage = (M & 1) && (2 * M + 2 < NGRP);
      if (doStage) vv = *(const float4*)&synTh[(2 * M + 2) * 64 + 4 * l];

      // f5 blocks for groups 2M+2 (p=0) and 2M+3 (p=1)
      int pos0 = (8 * M - 36) & 255;
      const float4* rp = (const float4*)&ring[s2][pos0];
      float e[36];
#pragma unroll
      for (int i = 0; i < 9; ++i) {
        float4 R = rp[i];
        e[4 * i + 0] = R.x; e[4 * i + 1] = R.y; e[4 * i + 2] = R.z; e[4 * i + 3] = R.w;
      }
      float f5v[2];
#pragma unroll
      for (int p = 0; p < 2; ++p) {
        float oo[4];
#pragma unroll
        for (int c = 0; c < 4; ++c) {
          v2f p01, p23, p45, p67, PR7, PR5, PR3, PR1;
          int ofs = 4 * p + 8 * c;
          p01.x = e[ofs + 0]; p01.y = e[ofs + 1];
          p23.x = e[ofs + 2]; p23.y = e[ofs + 3];
          p45.x = e[ofs + 4]; p45.y = e[ofs + 5];
          p67.x = e[ofs + 6]; p67.y = e[ofs + 7];
          PR7.x = hc5[31 - 8 * c]; PR7.y = hc5[30 - 8 * c];
          PR5.x = hc5[29 - 8 * c]; PR5.y = hc5[28 - 8 * c];
          PR3.x = hc5[27 - 8 * c]; PR3.y = hc5[26 - 8 * c];
          PR1.x = hc5[25 - 8 * c]; PR1.y = hc5[24 - 8 * c];
          v2f a = PR7 * p01; a += PR5 * p23; a += PR3 * p45; a += PR1 * p67;
          oo[c] = a.x + a.y;
        }
        f5v[p] = (oo[0] + oo[1]) + (oo[2] + oo[3]);   // matches quad_sum association
      }

      const int slot = M & 1, wbuf = (M + 1) & 1;
      float2 pa = *(const float2*)&oPartF[slot][0][l][0];
      float2 pb = *(const float2*)&oPartF[slot][1][l][0];
      float2 pc = *(const float2*)&oPartF[slot][2][l][0];
      float2 pd = *(const float2*)&oPartF[slot][3][l][0];
      float2 pe = *(const float2*)&oPartF[slot][4][l][0];
      float t0e = pa.x + pb.x;
      float t1e = pc.x + pd.x;
      float t2e = pe.x + f5v[0];
      farsumF[wbuf][0][l] = (t0e + t1e) + t2e;
      float t0o = pa.y + pb.y;
      float t1o = pc.y + pd.y;
      float t2o = pe.y + f5v[1];
      farsumF[wbuf][1][l] = (t0o + t1o) + t2o;

      if (doStage) {
        int e0 = (2 * M + 2) * 64 + 4 * l;
        int t0i = e0 >> 4, s0 = e0 & 15;
        int g = t0i >> 2, Kk = t0i & 3;
        int buf = (g >> 2) & 1;
        synStage[buf][g & 3][s0 + 0][Kk] = vv.x;
        synStage[buf][g & 3][s0 + 1][Kk] = vv.y;
        synStage[buf][g & 3][s0 + 2][Kk] = vv.z;
        synStage[buf][g & 3][s0 + 3][Kk] = vv.w;
      }

      bar_drain();   // ---- MID (farsumF/synStage for M+1 published)

      if ((M & 3) == 0 && M > 0) {
        int n = 2 * M;
        int We = (4 * n - 1) & 255;
        if (We < 191) We += 256;
        int base2 = We - 31;
#pragma unroll
        for (int r = 0; r < 2; ++r) {
          int eo = 64 * (n - 8) + 256 * r + 4 * l;
          int t0i = eo >> 4, s0 = eo & 15;
          int pos = base2 + (t0i - 4 * (n - 8));
          float4 w;
          w.x = ring[s0 + 0][pos]; w.y = ring[s0 + 1][pos];
          w.z = ring[s0 + 2][pos]; w.w = ring[s0 + 3][pos];
          *(float4*)&spk_out[eo] = w;
        }
      }
      bar_drain();   // ---- END
    }
    {   // tail: old-groups NGRP-8..NGRP-1
      int n = NGRP;
      int We = (4 * n - 1) & 255;
      if (We < 191) We += 256;
      int base2 = We - 31;
#pragma unroll
      for (int r = 0; r < 2; ++r) {
        int eo = 64 * (n - 8) + 256 * r + 4 * l;
        int t0i = eo >> 4, s0 = eo & 15;
        int pos = base2 + (t0i - 4 * (n - 8));
        float4 w;
        w.x = ring[s0 + 0][pos]; w.y = ring[s0 + 1][pos];
        w.z = ring[s0 + 2][pos]; w.w = ring[s0 + 3][pos];
        *(float4*)&spk_out[eo] = w;
      }
    }
  } else {
    // ===== far waves f=0..4 at widx {1,2,3,5,6}: groups 2M+4 (even), 2M+5 (odd) =====
    const int f = (widx < 4) ? (widx - 1) : (widx - 2);
    const int s2 = l >> 2, qq = l & 3;
    const float* hrow = filt + (48 + s2) * TNO;
    const int base = 196 - 32 * f - 8 * qq;
    float ca[11];
#pragma unroll
    for (int m = 0; m < 11; ++m) {
      int hidx = base + m;
      ca[m] = (hidx <= 199) ? hrow[hidx] : 0.f;
    }
    v2f pr[11];
    pr[0].x = 0.f; pr[0].y = 0.f;
#pragma unroll
    for (int m = 1; m < 11; ++m) { pr[m].x = ca[m]; pr[m].y = ca[m - 1]; }

    for (int M = 0; M < NSUP; ++M) {
      int W0 = (8 * M - 188 + 32 * f + 8 * qq) & 255;
      const float4* rp = (const float4*)&ring[s2][W0];
      float4 V0 = rp[0], V1 = rp[1], V2 = rp[2];
      v2f p01, p23, p45, p67, q01, q23, q45, q67;
      p01.x = V0.x; p01.y = V0.y; p23.x = V0.z; p23.y = V0.w;
      p45.x = V1.x; p45.y = V1.y; p67.x = V1.z; p67.y = V1.w;
      q01.x = V1.x; q01.y = V1.y; q23.x = V1.z; q23.y = V1.w;
      q45.x = V2.x; q45.y = V2.y; q67.x = V2.z; q67.y = V2.w;
      float o0, o1, o2, o3, o4, o5, o6, o7;
      { v2f a = pr[7] * p01;  a += pr[5] * p23; a += pr[3] * p45; a += pr[1] * p67; o0 = a.x + a.y; }
      { v2f a = pr[8] * p01;  a += pr[6] * p23; a += pr[4] * p45; a += pr[2] * p67; o1 = a.x + a.y; }
      { v2f a = pr[9] * p01;  a += pr[7] * p23; a += pr[5] * p45; a += pr[3] * p67; o2 = a.x + a.y; }
      { v2f a = pr[10] * p01; a += pr[8] * p23; a += pr[6] * p45; a += pr[4] * p67; o3 = a.x + a.y; }
      { v2f a = pr[7] * q01;  a += pr[5] * q23; a += pr[3] * q45; a += pr[1] * q67; o4 = a.x + a.y; }
      { v2f a = pr[8] * q01;  a += pr[6] * q23; a += pr[4] * q45; a += pr[2] * q67; o5 = a.x + a.y; }
      { v2f a = pr[9] * q01;  a += pr[7] * q23; a += pr[5] * q45; a += pr[3] * q67; o6 = a.x + a.y; }
      { v2f a = pr[10] * q01; a += pr[8] * q23; a += pr[6] * q45; a += pr[4] * q67; o7 = a.x + a.y; }
      o0 = quad_sum(o0); o1 = quad_sum(o1); o2 = quad_sum(o2); o3 = quad_sum(o3);
      o4 = quad_sum(o4); o5 = quad_sum(o5); o6 = quad_sum(o6); o7 = quad_sum(o7);
      float myoE = (qq == 0) ? o0 : (qq == 1) ? o1 : (qq == 2) ? o2 : o3;
      float myoO = (qq == 0) ? o4 : (qq == 1) ? o5 : (qq == 2) ? o6 : o7;
      const int slot = (M + 1) & 1;
      float2 w2; w2.x = myoE; w2.y = myoO;
      *(float2*)&oPartF[slot][f][l][0] = w2;
      bar_raw();     // ---- MID (oPartF writes drain at END)
      bar_drain();   // ---- END
    }
  }
}

extern "C" void kernel_launch(void* const* d_in, const int* in_sizes, int n_in,
                              void* d_out, int out_size, void* d_ws, size_t ws_size,
                              hipStream_t stream) {
  const float* S_e     = (const float*)d_in[0];
  const float* S_i     = (const float*)d_in[1];
  const float* C_den   = (const float*)d_in[2];
  const float* C_syn_e = (const float*)d_in[3];
  const float* C_syn_i = (const float*)d_in[4];
  const float* Tau_e   = (const float*)d_in[5];
  const float* Tau_i   = (const float*)d_in[6];
  const float* W_e     = (const float*)d_in[7];
  const float* W_i     = (const float*)d_in[8];
  const float* D_e     = (const float*)d_in[9];
  const float* D_i     = (const float*)d_in[10];
  const float* Tau_spk = (const float*)d_in[11];
  const float* W_spk   = (const float*)d_in[12];
  const float* W_hist  = (const float*)d_in[13];
  const float* Theta   = (const float*)d_in[14];

  float* out     = (float*)d_out;
  float* spk_out = out;            // 20000*16
  float* filt    = out + 320000;   // 64*200

  float* ws    = (float*)d_ws;
  float* syn_e = ws;               // 320000
  float* syn_i = ws + 320000;      // 320000
  float* synTh = ws + 640000;      // 320000  ([t][s] layout)

  filters_k<<<50, 256, 0, stream>>>(Tau_e, Tau_i, W_e, W_i, D_e, D_i,
                                    Tau_spk, W_spk, W_hist, filt);
  synmm_k<<<1250, 256, 0, stream>>>(S_e, C_syn_e, syn_e, E_NO_C);
  synmm_k<<<1250, 256, 0, stream>>>(S_i, C_syn_i, syn_i, I_NO_C);
  conv_k<<<1250, 256, 0, stream>>>(syn_e, syn_i, filt, Theta, synTh);
  scan22_k<<<1, 512, 0, stream>>>(synTh, filt, C_den, Tau_spk, W_spk, spk_out);
}

// Round 14
// 1751.020 us; speedup vs baseline: 1.1314x; 1.1314x over previous
//
#include <hip/hip_runtime.h>

#ifndef M_PI
#define M_PI 3.14159265358979323846
#endif

#define T_DATA 20000
#define E_NO_C 2000
#define I_NO_C 500
#define SUB 16
#define TNO 200
#define NGRP 5000   // 4-step groups
#define NSUP 2500   // 8-step super-groups

typedef float v2f __attribute__((ext_vector_type(2)));

template <bool B> struct BC { static constexpr bool v = B; };

// quad butterfly reduction on the VALU pipe (DPP quad_perm), no LDS traffic.
__device__ __forceinline__ float quad_sum(float v) {
  int a = __builtin_amdgcn_mov_dpp(__float_as_int(v), 177, 0xf, 0xf, true);
  v += __int_as_float(a);
  int b = __builtin_amdgcn_mov_dpp(__float_as_int(v), 78, 0xf, 0xf, true);
  v += __int_as_float(b);
  return v;
}

// Drain barrier: LDS writes visible after this (lgkmcnt(0) + s_barrier).
__device__ __forceinline__ void bar_drain() {
  asm volatile("s_waitcnt lgkmcnt(0)" ::: "memory");
  __builtin_amdgcn_s_barrier();
  asm volatile("" ::: "memory");
}
// Raw barrier: rendezvous only. Use when this wave's pending LDS ops are not
// consumed by anyone until a LATER drain barrier.
__device__ __forceinline__ void bar_raw() {
  asm volatile("" ::: "memory");
  __builtin_amdgcn_s_barrier();
  asm volatile("" ::: "memory");
}

// ---------------- Kernel A: filter kernels (e, i, spk, hist) -> d_out[320000..] ----------------
__global__ void filters_k(const float* __restrict__ Tau_e, const float* __restrict__ Tau_i,
                          const float* __restrict__ W_e,  const float* __restrict__ W_i,
                          const float* __restrict__ D_e,  const float* __restrict__ D_i,
                          const float* __restrict__ Tau_spk, const float* __restrict__ W_spk,
                          const float* __restrict__ W_hist,
                          float* __restrict__ filt_out) {
  int id = blockIdx.x * blockDim.x + threadIdx.x;
  if (id >= 64 * TNO) return;
  int r = id / TNO, x = id % TNO;
  int s = r & 15, kind = r >> 4;
  double xd = (double)x;
  double val;
  if (kind == 0) {
    double te = xd - exp((double)D_e[s]); te = te > 0.0 ? te : 0.0;
    double tt = te / exp((double)Tau_e[s]);
    val = tt * exp(-tt) * exp((double)W_e[s]);
  } else if (kind == 1) {
    double ti = xd - exp((double)D_i[s]); ti = ti > 0.0 ? ti : 0.0;
    double tt = ti / exp((double)Tau_i[s]);
    val = -tt * exp(-tt) * exp((double)W_i[s]);
  } else if (kind == 2) {
    double tt = xd / exp((double)Tau_spk[s]);
    val = tt * exp(-tt) * exp((double)W_spk[s]);
  } else {
    double raw = 4.0 * log(xd + 1.0);
    double acc = 0.0;
    for (int i = 0; i < 16; ++i) {
      double phi = (M_PI / 2.0) * (double)i;
      double b = (raw < phi - M_PI || raw > phi + M_PI) ? 0.0
                                                        : (0.5 * cos(raw - phi) + 0.5);
      acc += (double)W_hist[s * 16 + i] * b;
    }
    val = acc;
  }
  filt_out[id] = (float)val;
}

// ---------------- Kernel B: syn = S @ C^T, C staged in LDS tiles ----------------
#define ETILE 500
__global__ __launch_bounds__(256) void synmm_k(const float* __restrict__ S,
                                               const float* __restrict__ C,
                                               float* __restrict__ out, int E) {
  __shared__ __align__(16) float Cs[16][ETILE];
  int tid = threadIdx.x;
  int s = tid & 15, tt = tid >> 4;
  long t = (long)blockIdx.x * 16 + tt;
  const float* Srow = S + t * E;
  float acc = 0.f;
  for (int tb = 0; tb < E; tb += ETILE) {
    __syncthreads();
    for (int i = tid; i < 16 * ETILE; i += 256) {
      int s2 = i / ETILE, k2 = i - s2 * ETILE;
      Cs[s2][k2] = C[(long)s2 * E + tb + k2];
    }
    __syncthreads();
    const float* Crow = &Cs[s][0];
    const float* Sp = Srow + tb;
#pragma unroll 2
    for (int e = 0; e < ETILE; e += 4) {
      float4 a = *(const float4*)(Sp + e);
      float4 c = *(const float4*)(Crow + e);
      acc = fmaf(a.x, c.x, acc); acc = fmaf(a.y, c.y, acc);
      acc = fmaf(a.z, c.z, acc); acc = fmaf(a.w, c.w, acc);
    }
  }
  out[t * 16 + s] = acc;
}

// ---------------- Kernel C: causal depthwise conv + Theta, [t][s] layout ----------------
__global__ void conv_k(const float* __restrict__ syn_e, const float* __restrict__ syn_i,
                       const float* __restrict__ filt, const float* __restrict__ Theta,
                       float* __restrict__ synTh) {
  __shared__ float ek[16][201];
  __shared__ float ik[16][201];
  int tid = threadIdx.x;
  for (int idx = tid; idx < 16 * TNO; idx += 256) {
    ek[idx / TNO][idx % TNO] = filt[idx];
    ik[idx / TNO][idx % TNO] = filt[16 * TNO + idx];
  }
  __syncthreads();
  int s = tid & 15, tt = tid >> 4;
  int t = blockIdx.x * 16 + tt;
  float acc = Theta[s];
  if (t >= TNO) {
#pragma unroll 4
    for (int j = 0; j < TNO; ++j) {
      int u = t - 1 - j;
      acc += ek[s][j] * syn_e[u * 16 + s] + ik[s][j] * syn_i[u * 16 + s];
    }
  } else {
    for (int j = 0; j < t; ++j) {
      int u = t - 1 - j;
      acc += ek[s][j] * syn_e[u * 16 + s] + ik[s][j] * syn_i[u * 16 + s];
    }
  }
  synTh[t * 16 + s] = acc;
}

// ---------------- Kernel D: 8-wave, 2-barrier interval (R23 = R21, session best) ----------------
// Final configuration. Ledger: R13 unswitch (-22%), R15 SIMD-isolation+prefetch,
// R16 slim phase-1, R19/R21 stall-shadow rebalancing (trees into phase-1 tail),
// R20 P-trick (neutral-safe). R22's raw-carry (assembly at phase-1 TOP) regressed:
// work scheduled BEFORE the chain entry delays it 1:1 — stall shadows exist only
// after STEP 1. All remaining moves measured as losses in both directions.
__global__ __launch_bounds__(512, 1) void scan21_k(const float* __restrict__ synTh,
                                                   const float* __restrict__ filt,
                                                   const float* __restrict__ C_den,
                                                   const float* __restrict__ Tau_spk,
                                                   const float* __restrict__ W_spk,
                                                   float* __restrict__ spk_out) {
  __shared__ __align__(16) float ring[16][452];        // [s][pos], mirror pos+256 for pos<192
  __shared__ __align__(16) float oPartF[2][5][64][2];  // [slot][farwave][4s+K][parity]
  __shared__ __align__(16) float farsumF[2][2][64];    // [buf][parity][4s+K]
  __shared__ __align__(16) float synStage[2][4][16][20]; // [buf][g&3][s][K(+pad)]
  const int tid = threadIdx.x;
  const int widx = tid >> 6;
  const int l = tid & 63;
  const int s = l & 15, q = l >> 4;

  for (int i = tid; i < 16 * 452; i += 512) (&ring[0][0])[i] = 0.f;
  for (int i = tid; i < 2 * 5 * 64 * 2; i += 512) (&oPartF[0][0][0][0])[i] = 0.f;
  for (int i = tid; i < 2 * 2 * 64; i += 512) (&farsumF[0][0][0])[i] = 0.f;
  __syncthreads();
  if (widx == 7) {  // merged: preload synTh old-groups 0..3 (256 floats)
    int e0 = 4 * l;
    float4 v = *(const float4*)&synTh[e0];
    int t0 = e0 >> 4, s0 = e0 & 15;
    int g = t0 >> 2, K = t0 & 3;
    synStage[0][g & 3][s0 + 0][K] = v.x;
    synStage[0][g & 3][s0 + 1][K] = v.y;
    synStage[0][g & 3][s0 + 2][K] = v.z;
    synStage[0][g & 3][s0 + 3][K] = v.w;
  }
  __syncthreads();

  if (widx == 0) {
    // ================= scan wave (SIMD0, alone) =================
    const float* hrow = filt + (48 + s) * TNO;
    float hk[15];
#pragma unroll
    for (int i = 0; i < 15; ++i) hk[i] = hrow[i];

    float t0v = Tau_spk[0], w0v = W_spk[0];
    bool okrow = (Tau_spk[s] == t0v) && (W_spk[s] == w0v);
    unsigned cd = 0u;
#pragma unroll
    for (int j = 0; j < 16; ++j) {
      float cv = C_den[s * 16 + j];
      okrow = okrow && (cv == 0.f || cv == 1.f);
      cd |= (cv != 0.f) ? (1u << j) : 0u;
    }
    const bool uni = (bool)__all((int)okrow);

    const double tau  = exp((double)Tau_spk[s]);
    const double aa   = exp(-1.0 / tau);
    const double c2a  = exp((double)W_spk[s]) * aa / tau;  // K[d]=C(d-1)a^(d-1), C=w/tau
    const double twoa = 2.0 * aa;
    const double na2  = -aa * aa;

    double twoa4[4], na24[4], c2a4[4], yd0a[4], yd1a[4];
    float cden4[4];
#pragma unroll
    for (int r = 0; r < 4; ++r) {
      int j = 4 * q + r;
      double tj = exp((double)Tau_spk[j]);
      double aj = exp(-1.0 / tj);
      twoa4[r] = 2.0 * aj; na24[r] = -aj * aj;
      c2a4[r]  = exp((double)W_spk[j]) * aj / tj;
      yd0a[r] = 0.0; yd1a[r] = 0.0;
      cden4[r] = C_den[s * 16 + j];
    }

    double zA = 0.0, zB = 0.0, zP = 0.0;   // zP = fma(twoa,zB,na2*zA), off-chain
    float mixu = 0.f, mix1 = 0.f;
    float sgPrev = 0.f;
    float S0 = 0.f, S1 = 0.f, S2 = 0.f, S3 = 0.f;  // group 2M-1 spikes

    // ---- priming (M=0): phase2-equivalent assembly with zero trees ----
    float ocA0, ocA1, ocA2, ocA3;        // fully assembled A-side pre-activation
    float uB0, uB1, uB2, uB3;            // nrB + fsB
    float sB0, sB1, sB2, sB3;            // synB passthrough
    float ccBk0, ccBk1, ccBk2, ccBk3;    // ccB tree
    {
      float4 fsA_r = *(const float4*)&farsumF[0][0][4 * s];
      float4 fsB_r = *(const float4*)&farsumF[0][1][4 * s];
      float4 synA_r = *(const float4*)&synStage[0][0][s][0];
      float4 synB_r = *(const float4*)&synStage[0][1][s][0];
      float z0 = 0.f;
      ocA0 = ((z0 + fsA_r.x) + (synA_r.x + z0)) + z0;
      ocA1 = ((z0 + fsA_r.y) + (synA_r.y + z0)) + z0;
      ocA2 = ((z0 + fsA_r.z) + (synA_r.z + z0)) + z0;
      ocA3 = ((z0 + fsA_r.w) + (synA_r.w + z0)) + z0;
      uB0 = z0 + fsB_r.x; uB1 = z0 + fsB_r.y; uB2 = z0 + fsB_r.z; uB3 = z0 + fsB_r.w;
      sB0 = synB_r.x; sB1 = synB_r.y; sB2 = synB_r.z; sB3 = synB_r.w;
      ccBk0 = z0; ccBk1 = z0; ccBk2 = z0; ccBk3 = z0;
    }

#define STEP(SGD, PRE, SGOUT)                                                 \
    {                                                                         \
      float sub = fmaf(hk[0], (SGD), (PRE));                                  \
      unsigned long long bal = __ballot(sub > 0.f);                           \
      float sg = sub > 0.f ? 1.f : 0.f;                                       \
      if constexpr (UNI) {                                                    \
        unsigned xm = (unsigned)bal & cd;  /* cd bits 0-15 only */            \
        double zc = fma(c2a, (double)__popc(xm), zP);                         \
        zA = zB; zB = zc;                                                     \
        zP = fma(twoa, zB, na2 * zA);                                         \
        mixu = (float)zA;                                                     \
      } else {                                                                \
        unsigned mk = (unsigned)bal & 0xFFFFu;                                \
        float p = 0.f;                                                        \
        _Pragma("unroll")                                                     \
        for (int r = 0; r < 4; ++r) {                                         \
          double xr = (double)((mk >> (4 * q + r)) & 1u);                     \
          double y2 = fma(twoa4[r], yd1a[r], fma(na24[r], yd0a[r], c2a4[r] * xr)); \
          yd0a[r] = yd1a[r]; yd1a[r] = y2;                                    \
          p = fmaf(cden4[r], (float)y2, p);                                   \
        }                                                                     \
        p += __shfl_xor(p, 16); p += __shfl_xor(p, 32);                       \
        float mixn = mix1; mix1 = p;                                          \
        mixu = mixn;                                                          \
      }                                                                       \
      (SGOUT) = sg;                                                           \
    }

    auto scan_loop = [&](auto uc) {
      constexpr bool UNI = decltype(uc)::v;
      for (int M = 0; M < NSUP; ++M) {
        // ---------------- phase 1: STEP chain + stall-filler work ----------------
        float SA0, SA1, SA2, SA3;
        STEP(sgPrev, ocA0 + mixu, SA0)
        float pend2 = hk[1] * SA0;
        float pend3 = hk[2] * SA0;
        STEP(SA0, ocA1 + mixu, SA1)
        pend3 = fmaf(hk[1], SA1, pend3);
        STEP(SA1, (ocA2 + mixu) + pend2, SA2)
        STEP(SA2, (ocA3 + mixu) + pend3, SA3)

        if (l < 16) {
          int u = (8 * M) & 255;
          float4 w0; w0.x = SA0; w0.y = SA1; w0.z = SA2; w0.w = SA3;
          *(float4*)&ring[s][u] = w0;
          if (u < 192) *(float4*)&ring[s][u + 256] = w0;
        }

        // B-group: only cB is fresh; rest precomputed last interval.
        float cB0 = fmaf(hk[1], SA2, fmaf(hk[2], SA1, hk[3] * SA0));
        float cB1 = fmaf(hk[1], SA3, fmaf(hk[2], SA2, fmaf(hk[3], SA1, hk[4] * SA0)));
        float cB2 = fmaf(hk[2], SA3, fmaf(hk[3], SA2, fmaf(hk[4], SA1, hk[5] * SA0)));
        float cB3 = fmaf(hk[3], SA3, fmaf(hk[4], SA2, fmaf(hk[5], SA1, hk[6] * SA0)));
        float ocB0 = (uB0 + (sB0 + cB0)) + ccBk0;
        float ocB1 = (uB1 + (sB1 + cB1)) + ccBk1;
        float ocB2 = (uB2 + (sB2 + cB2)) + ccBk2;
        float ocB3 = (uB3 + (sB3 + cB3)) + ccBk3;

        float SB0, SB1, SB2, SB3;
        STEP(SA3, ocB0 + mixu, SB0)
        float pend2b = hk[1] * SB0;
        float pend3b = hk[2] * SB0;
        STEP(SB0, ocB1 + mixu, SB1)
        pend3b = fmaf(hk[1], SB1, pend3b);
        STEP(SB1, (ocB2 + mixu) + pend2b, SB2)
        STEP(SB2, (ocB3 + mixu) + pend3b, SB3)

        if (l < 16) {
          int u = (8 * M + 4) & 255;
          float4 w0; w0.x = SB0; w0.y = SB1; w0.z = SB2; w0.w = SB3;
          *(float4*)&ring[s][u] = w0;
          if (u < 192) *(float4*)&ring[s][u + 256] = w0;
        }

        // stall-filler trees for M+1 (inputs S, SA — independent of STEP
        // chain; scheduler interleaves them into chain stalls). Exact R9
        // nests; S still holds group 2M-1 (rotation happens in phase 2).
        float nrA0 = fmaf(hk[11], S0, fmaf(hk[10], S1, fmaf(hk[9], S2, hk[8] * S3)));
        float nrA1 = fmaf(hk[12], S0, fmaf(hk[11], S1, fmaf(hk[10], S2, hk[9] * S3)));
        float nrA2 = fmaf(hk[13], S0, fmaf(hk[12], S1, fmaf(hk[11], S2, hk[10] * S3)));
        float nrA3 = fmaf(hk[14], S0, fmaf(hk[13], S1, fmaf(hk[12], S2, hk[11] * S3)));
        float ccA0 = fmaf(hk[7], SA0, fmaf(hk[6], SA1, fmaf(hk[5], SA2, hk[4] * SA3)));
        float ccA1 = fmaf(hk[8], SA0, fmaf(hk[7], SA1, fmaf(hk[6], SA2, hk[5] * SA3)));
        float ccA2 = fmaf(hk[9], SA0, fmaf(hk[8], SA1, fmaf(hk[7], SA2, hk[6] * SA3)));
        float ccA3 = fmaf(hk[10], SA0, fmaf(hk[9], SA1, fmaf(hk[8], SA2, hk[7] * SA3)));
        float nrB0 = fmaf(hk[11], SA0, fmaf(hk[10], SA1, fmaf(hk[9], SA2, hk[8] * SA3)));
        float nrB1 = fmaf(hk[12], SA0, fmaf(hk[11], SA1, fmaf(hk[10], SA2, hk[9] * SA3)));
        float nrB2 = fmaf(hk[13], SA0, fmaf(hk[12], SA1, fmaf(hk[11], SA2, hk[10] * SA3)));
        float nrB3 = fmaf(hk[14], SA0, fmaf(hk[13], SA1, fmaf(hk[12], SA2, hk[11] * SA3)));

        // SB-dependent trees for M+1 (R21): SB0 is ready at STEP 5, so
        // hk3*SB0 etc. interleave into STEPs 6-8's stall slots and the
        // step-8 z-tail shadow. Exact R9 nests.
        float cA0 = fmaf(hk[1], SB2, fmaf(hk[2], SB1, hk[3] * SB0));
        float cA1 = fmaf(hk[1], SB3, fmaf(hk[2], SB2, fmaf(hk[3], SB1, hk[4] * SB0)));
        float cA2 = fmaf(hk[2], SB3, fmaf(hk[3], SB2, fmaf(hk[4], SB1, hk[5] * SB0)));
        float cA3 = fmaf(hk[3], SB3, fmaf(hk[4], SB2, fmaf(hk[5], SB1, hk[6] * SB0)));
        float ccB0 = fmaf(hk[7], SB0, fmaf(hk[6], SB1, fmaf(hk[5], SB2, hk[4] * SB3)));
        float ccB1 = fmaf(hk[8], SB0, fmaf(hk[7], SB1, fmaf(hk[6], SB2, hk[5] * SB3)));
        float ccB2 = fmaf(hk[9], SB0, fmaf(hk[8], SB1, fmaf(hk[7], SB2, hk[6] * SB3)));
        float ccB3 = fmaf(hk[10], SB0, fmaf(hk[9], SB1, fmaf(hk[8], SB2, hk[7] * SB3)));

        bar_raw();   // ---- MID (ring writes drain at END)

        // ---------------- phase 2: prefetch + assembly for M+1 ----------------
        const int Mn = M + 1;
        const int gAn = 2 * Mn, gBn = 2 * Mn + 1;
        float4 fsA_r = *(const float4*)&farsumF[Mn & 1][0][4 * s];
        float4 fsB_r = *(const float4*)&farsumF[Mn & 1][1][4 * s];
        float4 synA_r = *(const float4*)&synStage[(gAn >> 2) & 1][gAn & 3][s][0];
        float4 synB_r = *(const float4*)&synStage[(gBn >> 2) & 1][gBn & 3][s][0];

        // full A assembly (exact tree): oc = ((nr + fs) + (syn + c)) + cc
        ocA0 = ((nrA0 + fsA_r.x) + (synA_r.x + cA0)) + ccA0;
        ocA1 = ((nrA1 + fsA_r.y) + (synA_r.y + cA1)) + ccA1;
        ocA2 = ((nrA2 + fsA_r.z) + (synA_r.z + cA2)) + ccA2;
        ocA3 = ((nrA3 + fsA_r.w) + (synA_r.w + cA3)) + ccA3;
        // B partials
        uB0 = nrB0 + fsB_r.x; uB1 = nrB1 + fsB_r.y;
        uB2 = nrB2 + fsB_r.z; uB3 = nrB3 + fsB_r.w;
        sB0 = synB_r.x; sB1 = synB_r.y; sB2 = synB_r.z; sB3 = synB_r.w;
        ccBk0 = ccB0; ccBk1 = ccB1; ccBk2 = ccB2; ccBk3 = ccB3;

        S0 = SB0; S1 = SB1; S2 = SB2; S3 = SB3;
        sgPrev = SB3;
        bar_drain();   // ---- END (ring writes + phase2 reads drained)
      }
    };
    if (uni) scan_loop(BC<true>{});
    else     scan_loop(BC<false>{});
#undef STEP
  } else if (widx == 4) {
    // ================= dummy wave (SIMD0): barriers only =================
    for (int M = 0; M < NSUP; ++M) {
      bar_raw();
      bar_raw();
    }
  } else if (widx == 7) {
    // ======== merged wave (SIMD3): f5-inline + farsum + staging + writeback ========
    const int s2 = l >> 2, K = l & 3;
    const float* hrow = filt + (48 + s2) * TNO;
    float hc5[32];   // hc5[x] = hrow[12+K+x]
#pragma unroll
    for (int x = 0; x < 32; ++x) hc5[x] = hrow[12 + K + x];

    for (int M = 0; M < NSUP; ++M) {
      float4 vv;
      const bool doStage = (M & 1) && (2 * M + 2 < NGRP);
      if (doStage) vv = *(const float4*)&synTh[(2 * M + 2) * 64 + 4 * l];

      // f5 blocks for groups 2M+2 (p=0) and 2M+3 (p=1)
      int pos0 = (8 * M - 36) & 255;
      const float4* rp = (const float4*)&ring[s2][pos0];
      float e[36];
#pragma unroll
      for (int i = 0; i < 9; ++i) {
        float4 R = rp[i];
        e[4 * i + 0] = R.x; e[4 * i + 1] = R.y; e[4 * i + 2] = R.z; e[4 * i + 3] = R.w;
      }
      float f5v[2];
#pragma unroll
      for (int p = 0; p < 2; ++p) {
        float oo[4];
#pragma unroll
        for (int c = 0; c < 4; ++c) {
          v2f p01, p23, p45, p67, PR7, PR5, PR3, PR1;
          int ofs = 4 * p + 8 * c;
          p01.x = e[ofs + 0]; p01.y = e[ofs + 1];
          p23.x = e[ofs + 2]; p23.y = e[ofs + 3];
          p45.x = e[ofs + 4]; p45.y = e[ofs + 5];
          p67.x = e[ofs + 6]; p67.y = e[ofs + 7];
          PR7.x = hc5[31 - 8 * c]; PR7.y = hc5[30 - 8 * c];
          PR5.x = hc5[29 - 8 * c]; PR5.y = hc5[28 - 8 * c];
          PR3.x = hc5[27 - 8 * c]; PR3.y = hc5[26 - 8 * c];
          PR1.x = hc5[25 - 8 * c]; PR1.y = hc5[24 - 8 * c];
          v2f a = PR7 * p01; a += PR5 * p23; a += PR3 * p45; a += PR1 * p67;
          oo[c] = a.x + a.y;
        }
        f5v[p] = (oo[0] + oo[1]) + (oo[2] + oo[3]);   // matches quad_sum association
      }

      const int slot = M & 1, wbuf = (M + 1) & 1;
      float2 pa = *(const float2*)&oPartF[slot][0][l][0];
      float2 pb = *(const float2*)&oPartF[slot][1][l][0];
      float2 pc = *(const float2*)&oPartF[slot][2][l][0];
      float2 pd = *(const float2*)&oPartF[slot][3][l][0];
      float2 pe = *(const float2*)&oPartF[slot][4][l][0];
      float t0e = pa.x + pb.x;
      float t1e = pc.x + pd.x;
      float t2e = pe.x + f5v[0];
      farsumF[wbuf][0][l] = (t0e + t1e) + t2e;
      float t0o = pa.y + pb.y;
      float t1o = pc.y + pd.y;
      float t2o = pe.y + f5v[1];
      farsumF[wbuf][1][l] = (t0o + t1o) + t2o;

      if (doStage) {
        int e0 = (2 * M + 2) * 64 + 4 * l;
        int t0i = e0 >> 4, s0 = e0 & 15;
        int g = t0i >> 2, Kk = t0i & 3;
        int buf = (g >> 2) & 1;
        synStage[buf][g & 3][s0 + 0][Kk] = vv.x;
        synStage[buf][g & 3][s0 + 1][Kk] = vv.y;
        synStage[buf][g & 3][s0 + 2][Kk] = vv.z;
        synStage[buf][g & 3][s0 + 3][Kk] = vv.w;
      }

      bar_drain();   // ---- MID (farsumF/synStage for M+1 published)

      if ((M & 3) == 0 && M > 0) {
        int n = 2 * M;
        int We = (4 * n - 1) & 255;
        if (We < 191) We += 256;
        int base2 = We - 31;
#pragma unroll
        for (int r = 0; r < 2; ++r) {
          int eo = 64 * (n - 8) + 256 * r + 4 * l;
          int t0i = eo >> 4, s0 = eo & 15;
          int pos = base2 + (t0i - 4 * (n - 8));
          float4 w;
          w.x = ring[s0 + 0][pos]; w.y = ring[s0 + 1][pos];
          w.z = ring[s0 + 2][pos]; w.w = ring[s0 + 3][pos];
          *(float4*)&spk_out[eo] = w;
        }
      }
      bar_drain();   // ---- END
    }
    {   // tail: old-groups NGRP-8..NGRP-1
      int n = NGRP;
      int We = (4 * n - 1) & 255;
      if (We < 191) We += 256;
      int base2 = We - 31;
#pragma unroll
      for (int r = 0; r < 2; ++r) {
        int eo = 64 * (n - 8) + 256 * r + 4 * l;
        int t0i = eo >> 4, s0 = eo & 15;
        int pos = base2 + (t0i - 4 * (n - 8));
        float4 w;
        w.x = ring[s0 + 0][pos]; w.y = ring[s0 + 1][pos];
        w.z = ring[s0 + 2][pos]; w.w = ring[s0 + 3][pos];
        *(float4*)&spk_out[eo] = w;
      }
    }
  } else {
    // ===== far waves f=0..4 at widx {1,2,3,5,6}: groups 2M+4 (even), 2M+5 (odd) =====
    const int f = (widx < 4) ? (widx - 1) : (widx - 2);
    const int s2 = l >> 2, qq = l & 3;
    const float* hrow = filt + (48 + s2) * TNO;
    const int base = 196 - 32 * f - 8 * qq;
    float ca[11];
#pragma unroll
    for (int m = 0; m < 11; ++m) {
      int hidx = base + m;
      ca[m] = (hidx <= 199) ? hrow[hidx] : 0.f;
    }
    v2f pr[11];
    pr[0].x = 0.f; pr[0].y = 0.f;
#pragma unroll
    for (int m = 1; m < 11; ++m) { pr[m].x = ca[m]; pr[m].y = ca[m - 1]; }

    for (int M = 0; M < NSUP; ++M) {
      int W0 = (8 * M - 188 + 32 * f + 8 * qq) & 255;
      const float4* rp = (const float4*)&ring[s2][W0];
      float4 V0 = rp[0], V1 = rp[1], V2 = rp[2];
      v2f p01, p23, p45, p67, q01, q23, q45, q67;
      p01.x = V0.x; p01.y = V0.y; p23.x = V0.z; p23.y = V0.w;
      p45.x = V1.x; p45.y = V1.y; p67.x = V1.z; p67.y = V1.w;
      q01.x = V1.x; q01.y = V1.y; q23.x = V1.z; q23.y = V1.w;
      q45.x = V2.x; q45.y = V2.y; q67.x = V2.z; q67.y = V2.w;
      float o0, o1, o2, o3, o4, o5, o6, o7;
      { v2f a = pr[7] * p01;  a += pr[5] * p23; a += pr[3] * p45; a += pr[1] * p67; o0 = a.x + a.y; }
      { v2f a = pr[8] * p01;  a += pr[6] * p23; a += pr[4] * p45; a += pr[2] * p67; o1 = a.x + a.y; }
      { v2f a = pr[9] * p01;  a += pr[7] * p23; a += pr[5] * p45; a += pr[3] * p67; o2 = a.x + a.y; }
      { v2f a = pr[10] * p01; a += pr[8] * p23; a += pr[6] * p45; a += pr[4] * p67; o3 = a.x + a.y; }
      { v2f a = pr[7] * q01;  a += pr[5] * q23; a += pr[3] * q45; a += pr[1] * q67; o4 = a.x + a.y; }
      { v2f a = pr[8] * q01;  a += pr[6] * q23; a += pr[4] * q45; a += pr[2] * q67; o5 = a.x + a.y; }
      { v2f a = pr[9] * q01;  a += pr[7] * q23; a += pr[5] * q45; a += pr[3] * q67; o6 = a.x + a.y; }
      { v2f a = pr[10] * q01; a += pr[8] * q23; a += pr[6] * q45; a += pr[4] * q67; o7 = a.x + a.y; }
      o0 = quad_sum(o0); o1 = quad_sum(o1); o2 = quad_sum(o2); o3 = quad_sum(o3);
      o4 = quad_sum(o4); o5 = quad_sum(o5); o6 = quad_sum(o6); o7 = quad_sum(o7);
      float myoE = (qq == 0) ? o0 : (qq == 1) ? o1 : (qq == 2) ? o2 : o3;
      float myoO = (qq == 0) ? o4 : (qq == 1) ? o5 : (qq == 2) ? o6 : o7;
      const int slot = (M + 1) & 1;
      float2 w2; w2.x = myoE; w2.y = myoO;
      *(float2*)&oPartF[slot][f][l][0] = w2;
      bar_raw();     // ---- MID (oPartF writes drain at END)
      bar_drain();   // ---- END
    }
  }
}

extern "C" void kernel_launch(void* const* d_in, const int* in_sizes, int n_in,
                              void* d_out, int out_size, void* d_ws, size_t ws_size,
                              hipStream_t stream) {
  const float* S_e     = (const float*)d_in[0];
  const float* S_i     = (const float*)d_in[1];
  const float* C_den   = (const float*)d_in[2];
  const float* C_syn_e = (const float*)d_in[3];
  const float* C_syn_i = (const float*)d_in[4];
  const float* Tau_e   = (const float*)d_in[5];
  const float* Tau_i   = (const float*)d_in[6];
  const float* W_e     = (const float*)d_in[7];
  const float* W_i     = (const float*)d_in[8];
  const float* D_e     = (const float*)d_in[9];
  const float* D_i     = (const float*)d_in[10];
  const float* Tau_spk = (const float*)d_in[11];
  const float* W_spk   = (const float*)d_in[12];
  const float* W_hist  = (const float*)d_in[13];
  const float* Theta   = (const float*)d_in[14];

  float* out     = (float*)d_out;
  float* spk_out = out;            // 20000*16
  float* filt    = out + 320000;   // 64*200

  float* ws    = (float*)d_ws;
  float* syn_e = ws;               // 320000
  float* syn_i = ws + 320000;      // 320000
  float* synTh = ws + 640000;      // 320000  ([t][s] layout)

  filters_k<<<50, 256, 0, stream>>>(Tau_e, Tau_i, W_e, W_i, D_e, D_i,
                                    Tau_spk, W_spk, W_hist, filt);
  synmm_k<<<1250, 256, 0, stream>>>(S_e, C_syn_e, syn_e, E_NO_C);
  synmm_k<<<1250, 256, 0, stream>>>(S_i, C_syn_i, syn_i, I_NO_C);
  conv_k<<<1250, 256, 0, stream>>>(syn_e, syn_i, filt, Theta, synTh);
  scan21_k<<<1, 512, 0, stream>>>(synTh, filt, C_den, Tau_spk, W_spk, spk_out);
}